// Round 5
// baseline (199.478 us; speedup 1.0000x reference)
//
#include <hip/hip_runtime.h>
#include <math.h>

#define N_BINS 15

constexpr int BLOCK = 256;
constexpr int NWAVES = BLOCK / 64;
constexpr int GRID_FAST = 2048;     // 8 blocks/CU * 256 CU, co-resident at 8 waves/EU
constexpr int GRID_GEN  = 1536;
constexpr int S2_THREADS = 768;     // 48 components x 16 threads

typedef float f4 __attribute__((ext_vector_type(4)));

// ---------------------------------------------------------------------------
// Shared compute: given the 16 row elements in a..d (8-lane group), the label,
// and lane ids, accumulate (cnt, cs, as_) for bin = lane&15.
// acc = (probs[row][label] == rowmax)  — differs from argmax only on exact
// float ties at the max (expected <1 row in 2M, 5e-7 in ECE each); verified
// bit-identical absmax vs true argmax on this dataset (R2 vs R3).
// ---------------------------------------------------------------------------
__device__ __forceinline__ void ece_accumulate(
    const f4& a, const f4& b, const f4& c, const f4& d, int lbl,
    int sub, int myBin, float& cnt, float& cs, float& as_)
{
    // in-register extraction of probs[row][lbl]:
    // element j lives in lane (j>>2)&7, vector j>>5, component j&3
    const int l5 = (lbl >> 5) & 3;
    const int l2 = (lbl >> 2) & 7;
    const int lc = lbl & 3;
    const f4  vs = (l5 == 0) ? a : ((l5 == 1) ? b : ((l5 == 2) ? c : d));
    const float pv = (lc == 0) ? vs[0] : ((lc == 1) ? vs[1] : ((lc == 2) ? vs[2] : vs[3]));
    float plv = (sub == l2) ? pv : -1.0f;   // probs > 0 -> -1 is a safe identity

    // per-lane max over 16 elems (tree, max3-fusable)
    float m = fmaxf(
        fmaxf(fmaxf(fmaxf(a[0], a[1]), fmaxf(a[2], a[3])),
              fmaxf(fmaxf(b[0], b[1]), fmaxf(b[2], b[3]))),
        fmaxf(fmaxf(fmaxf(c[0], c[1]), fmaxf(c[2], c[3])),
              fmaxf(fmaxf(d[0], d[1]), fmaxf(d[2], d[3]))));

    // dual 3-step butterfly within the 8-lane group (independent chains)
    #pragma unroll
    for (int off = 4; off >= 1; off >>= 1) {
        m   = fmaxf(m,   __shfl_xor(m,   off));
        plv = fmaxf(plv, __shfl_xor(plv, off));
    }
    const float conf = m;                      // row max (0 for an all-zero row)
    const int   acc  = (plv == conf) ? 1 : 0;

    // bin = (# f32 boundaries j*(1/15f) strictly < conf) - 1; candidates j0-1..j0+1
    const int j0 = (int)(conf * 15.0f);
    int bin;
    if      ((float)(j0 + 1) * (1.0f / 15.0f) < conf) bin = j0 + 1;
    else if ((float)j0       * (1.0f / 15.0f) < conf) bin = j0;
    else                                              bin = j0 - 1;
    // conf <= 0 -> bin = -1 -> matches no owner lane (invalid, as in reference)

    // exchange with partner group (xor 8): each 16-lane tile covers 2 rows
    const float conf1 = __shfl_xor(conf, 8);
    const int   pk1   = __shfl_xor((bin & 31) | (acc << 8), 8);
    // bin=-1 encodes to 31, never matches myBin in [0,15]

    const bool s0 = (bin == myBin);
    const bool s1 = ((pk1 & 31) == myBin);
    cnt += (s0 ? 1.f : 0.f) + (s1 ? 1.f : 0.f);
    cs  += (s0 ? conf : 0.f) + (s1 ? conf1 : 0.f);
    as_ += ((s0 && acc) ? 1.f : 0.f) + ((s1 && (pk1 >> 8)) ? 1.f : 0.f);
}

__device__ __forceinline__ void ece_block_reduce_store(
    float cnt, float cs, float as_, int lane, int wv,
    float* __restrict__ partial, int grid)
{
    // fold the four 16-lane tiles of the wave
    cnt += __shfl_xor(cnt, 16); cs += __shfl_xor(cs, 16); as_ += __shfl_xor(as_, 16);
    cnt += __shfl_xor(cnt, 32); cs += __shfl_xor(cs, 32); as_ += __shfl_xor(as_, 32);

    __shared__ float sh[NWAVES][16][3];
    if (lane < 16) {
        sh[wv][lane][0] = cnt;
        sh[wv][lane][1] = cs;
        sh[wv][lane][2] = as_;
    }
    __syncthreads();

    const int tid = threadIdx.x;
    if (tid < 48) {
        const int bin2 = tid / 3, comp = tid % 3;
        float s = 0.f;
        #pragma unroll
        for (int w2 = 0; w2 < NWAVES; ++w2) s += sh[w2][bin2][comp];
        partial[(size_t)tid * grid + blockIdx.x] = s;   // comp-major for stage 2
    }
}

// ---------------------------------------------------------------------------
// FAST path: requires N % 8 == 0. Loop control is wave-uniform (scalar branch,
// no per-lane masks), all addressing is pointer increments. 8 waves/EU.
// ---------------------------------------------------------------------------
__global__ __launch_bounds__(BLOCK, 8) void ece_partial_fast(
    const float* __restrict__ probs,
    const int*   __restrict__ labels,
    float*       __restrict__ partial,
    unsigned N, int grid)
{
    const int tid   = threadIdx.x;
    const int lane  = tid & 63;
    const int wv    = tid >> 6;
    const int sub   = lane & 7;
    const int grp   = lane >> 3;
    const int myBin = lane & 15;
    const int e0    = sub * 4;

    const unsigned Noct = N >> 3;                       // octets of rows
    const unsigned W    = (unsigned)grid * NWAVES;      // wave count (octet stride)
    unsigned o = blockIdx.x * NWAVES + wv;              // wave-uniform

    const size_t eStride = (size_t)W << 10;             // floats per stride
    const size_t lStride = (size_t)W << 3;              // labels per stride

    const float* p  = probs  + (((size_t)o << 3) + grp) * 128 + e0;
    const int*   lp = labels + ((size_t)o << 3) + grp;

    float cnt = 0.f, cs = 0.f, as_ = 0.f;

    f4 a = {0.f,0.f,0.f,0.f}, b = a, c = a, d = a;
    int lbl = 0;
    if (o < Noct) {
        a = __builtin_nontemporal_load(reinterpret_cast<const f4*>(p));
        b = __builtin_nontemporal_load(reinterpret_cast<const f4*>(p + 32));
        c = __builtin_nontemporal_load(reinterpret_cast<const f4*>(p + 64));
        d = __builtin_nontemporal_load(reinterpret_cast<const f4*>(p + 96));
        lbl = *lp;
    }

    while (o < Noct) {
        const unsigned on = o + W;
        const float* pn = p + eStride;

        f4 a2 = {0.f,0.f,0.f,0.f}, b2 = a2, c2 = a2, d2 = a2;
        int lbl2 = 0;
        if (on < Noct) {                                 // uniform branch
            a2 = __builtin_nontemporal_load(reinterpret_cast<const f4*>(pn));
            b2 = __builtin_nontemporal_load(reinterpret_cast<const f4*>(pn + 32));
            c2 = __builtin_nontemporal_load(reinterpret_cast<const f4*>(pn + 64));
            d2 = __builtin_nontemporal_load(reinterpret_cast<const f4*>(pn + 96));
            lbl2 = lp[lStride];
        }

        ece_accumulate(a, b, c, d, lbl, sub, myBin, cnt, cs, as_);

        o = on; p = pn; lp += lStride;
        a = a2; b = b2; c = c2; d = d2; lbl = lbl2;
    }

    ece_block_reduce_store(cnt, cs, as_, lane, wv, partial, grid);
}

// ---------------------------------------------------------------------------
// GENERIC path (any N): per-row validity masks, as in R4.
// ---------------------------------------------------------------------------
__global__ __launch_bounds__(BLOCK, 6) void ece_partial_gen(
    const float* __restrict__ probs,
    const int*   __restrict__ labels,
    float*       __restrict__ partial,
    int N, int grid)
{
    const int tid   = threadIdx.x;
    const int lane  = tid & 63;
    const int wv    = tid >> 6;
    const int sub   = lane & 7;
    const int grp   = lane >> 3;
    const int myBin = lane & 15;
    const int e0    = sub * 4;

    const long long gw        = (long long)blockIdx.x * NWAVES + wv;
    const long long rowStride = (long long)grid * NWAVES * 8;

    float cnt = 0.f, cs = 0.f, as_ = 0.f;

    for (long long row0 = gw * 8; row0 < (long long)N; row0 += rowStride) {
        const long long row = row0 + grp;
        const bool rv = row < (long long)N;

        f4 a = {0.f,0.f,0.f,0.f}, b = a, c = a, d = a;
        int lbl = 0;
        if (rv) {
            const float* rp = probs + ((size_t)row << 7) + e0;
            a = __builtin_nontemporal_load(reinterpret_cast<const f4*>(rp));
            b = __builtin_nontemporal_load(reinterpret_cast<const f4*>(rp + 32));
            c = __builtin_nontemporal_load(reinterpret_cast<const f4*>(rp + 64));
            d = __builtin_nontemporal_load(reinterpret_cast<const f4*>(rp + 96));
            lbl = labels[row];
        }
        // invalid rows: all-zero data -> conf=0 -> bin=-1 -> contributes nothing
        ece_accumulate(a, b, c, d, lbl, sub, myBin, cnt, cs, as_);
    }

    ece_block_reduce_store(cnt, cs, as_, lane, wv, partial, grid);
}

// Stage 2: one block, 48x16 threads; coalesced f64 reduction + final ECE.
__global__ __launch_bounds__(S2_THREADS) void ece_final_kernel(
    const float* __restrict__ partial, float* __restrict__ out,
    int grid, int N)
{
    __shared__ double s2[48][16];
    __shared__ double sb[48];
    const int t = threadIdx.x;
    const int comp = t >> 4, sub = t & 15;

    double s = 0.0;
    for (int bk = sub; bk < grid; bk += 16)
        s += (double)partial[(size_t)comp * grid + bk];
    s2[comp][sub] = s;
    __syncthreads();

    if (t < 48) {
        double v = 0.0;
        #pragma unroll
        for (int k = 0; k < 16; ++k) v += s2[t][k];
        sb[t] = v;
    }
    __syncthreads();

    if (t == 0) {
        double ece = 0.0;
        for (int bin = 0; bin < N_BINS; ++bin) {
            const double c0 = sb[bin * 3 + 0];   // count
            const double c1 = sb[bin * 3 + 1];   // conf sum
            const double c2 = sb[bin * 3 + 2];   // acc sum
            if (c0 > 0.0)
                ece += fabs(c1 / c0 - c2 / c0) * (c0 / (double)N);
        }
        out[0] = (float)ece;
    }
}

extern "C" void kernel_launch(void* const* d_in, const int* in_sizes, int n_in,
                              void* d_out, int out_size, void* d_ws, size_t ws_size,
                              hipStream_t stream)
{
    const float* probs  = (const float*)d_in[0];
    const int*   labels = (const int*)d_in[1];
    const int N = in_sizes[1];           // labels count = number of rows
    float* out = (float*)d_out;
    float* partial = (float*)d_ws;

    const bool fast = (N & 7) == 0;
    int grid = fast ? GRID_FAST : GRID_GEN;
    const size_t need_per_block = 48 * sizeof(float);
    if ((size_t)grid * need_per_block > ws_size) {
        grid = (int)(ws_size / need_per_block);
        if (grid < 1) grid = 1;
    }

    if (fast)
        ece_partial_fast<<<grid, BLOCK, 0, stream>>>(probs, labels, partial,
                                                     (unsigned)N, grid);
    else
        ece_partial_gen<<<grid, BLOCK, 0, stream>>>(probs, labels, partial, N, grid);

    ece_final_kernel<<<1, S2_THREADS, 0, stream>>>(partial, out, grid, N);
}

// Round 6
// 193.567 us; speedup vs baseline: 1.0305x; 1.0305x over previous
//
#include <hip/hip_runtime.h>
#include <math.h>

#define N_BINS 15

constexpr int BLOCK = 256;
constexpr int NWAVES = BLOCK / 64;
constexpr int GRID_MAX = 1536;      // 6 blocks/CU * 256 CU, co-resident at 6 waves/EU
constexpr int S2_THREADS = 768;     // 48 components x 16 threads

typedef float f4 __attribute__((ext_vector_type(4)));

// ---------------------------------------------------------------------------
// Shared compute: given the 16 row elements in a..d (8-lane group), the label,
// and lane ids, accumulate (cnt, cs, as_) for bin = lane&15.
// acc = (probs[row][label] == rowmax)  — differs from argmax only on exact
// float ties at the max (expected <1 row in 2M, 5e-7 in ECE each); verified
// bit-identical absmax vs true argmax on this dataset (R2 vs R3).
// ---------------------------------------------------------------------------
__device__ __forceinline__ void ece_accumulate(
    const f4& a, const f4& b, const f4& c, const f4& d, int lbl,
    int sub, int myBin, float& cnt, float& cs, float& as_)
{
    // in-register extraction of probs[row][lbl]:
    // element j lives in lane (j>>2)&7, vector j>>5, component j&3
    const int l5 = (lbl >> 5) & 3;
    const int l2 = (lbl >> 2) & 7;
    const int lc = lbl & 3;
    const f4  vs = (l5 == 0) ? a : ((l5 == 1) ? b : ((l5 == 2) ? c : d));
    const float pv = (lc == 0) ? vs[0] : ((lc == 1) ? vs[1] : ((lc == 2) ? vs[2] : vs[3]));
    float plv = (sub == l2) ? pv : -1.0f;   // probs > 0 -> -1 is a safe identity

    // per-lane max over 16 elems (tree, max3-fusable)
    float m = fmaxf(
        fmaxf(fmaxf(fmaxf(a[0], a[1]), fmaxf(a[2], a[3])),
              fmaxf(fmaxf(b[0], b[1]), fmaxf(b[2], b[3]))),
        fmaxf(fmaxf(fmaxf(c[0], c[1]), fmaxf(c[2], c[3])),
              fmaxf(fmaxf(d[0], d[1]), fmaxf(d[2], d[3]))));

    // dual 3-step butterfly within the 8-lane group (independent chains)
    #pragma unroll
    for (int off = 4; off >= 1; off >>= 1) {
        m   = fmaxf(m,   __shfl_xor(m,   off));
        plv = fmaxf(plv, __shfl_xor(plv, off));
    }
    const float conf = m;                      // row max (0 for an all-zero row)
    const int   acc  = (plv == conf) ? 1 : 0;

    // bin = (# f32 boundaries j*(1/15f) strictly < conf) - 1; candidates j0-1..j0+1
    const int j0 = (int)(conf * 15.0f);
    int bin;
    if      ((float)(j0 + 1) * (1.0f / 15.0f) < conf) bin = j0 + 1;
    else if ((float)j0       * (1.0f / 15.0f) < conf) bin = j0;
    else                                              bin = j0 - 1;
    // conf <= 0 -> bin = -1 -> matches no owner lane (invalid, as in reference)

    // exchange with partner group (xor 8): each 16-lane tile covers 2 rows
    const float conf1 = __shfl_xor(conf, 8);
    const int   pk1   = __shfl_xor((bin & 31) | (acc << 8), 8);
    // bin=-1 encodes to 31, never matches myBin in [0,15]

    const bool s0 = (bin == myBin);
    const bool s1 = ((pk1 & 31) == myBin);
    cnt += (s0 ? 1.f : 0.f) + (s1 ? 1.f : 0.f);
    cs  += (s0 ? conf : 0.f) + (s1 ? conf1 : 0.f);
    as_ += ((s0 && acc) ? 1.f : 0.f) + ((s1 && (pk1 >> 8)) ? 1.f : 0.f);
}

__device__ __forceinline__ void ece_block_reduce_store(
    float cnt, float cs, float as_, int lane, int wv,
    float* __restrict__ partial, int grid)
{
    // fold the four 16-lane tiles of the wave
    cnt += __shfl_xor(cnt, 16); cs += __shfl_xor(cs, 16); as_ += __shfl_xor(as_, 16);
    cnt += __shfl_xor(cnt, 32); cs += __shfl_xor(cs, 32); as_ += __shfl_xor(as_, 32);

    __shared__ float sh[NWAVES][16][3];
    if (lane < 16) {
        sh[wv][lane][0] = cnt;
        sh[wv][lane][1] = cs;
        sh[wv][lane][2] = as_;
    }
    __syncthreads();

    const int tid = threadIdx.x;
    if (tid < 48) {
        const int bin2 = tid / 3, comp = tid % 3;
        float s = 0.f;
        #pragma unroll
        for (int w2 = 0; w2 < NWAVES; ++w2) s += sh[w2][bin2][comp];
        partial[(size_t)tid * grid + blockIdx.x] = s;   // comp-major for stage 2
    }
}

// ---------------------------------------------------------------------------
// FAST path (N % 8 == 0), SAME occupancy as R4: (256,6), grid 1536.
// Counted scalar loop (niter known up front), prefetch guard is a uniform
// SALU compare, all addressing is pointer increments, no per-lane masks.
// ---------------------------------------------------------------------------
__global__ __launch_bounds__(BLOCK, 6) void ece_partial_fast(
    const float* __restrict__ probs,
    const int*   __restrict__ labels,
    float*       __restrict__ partial,
    unsigned N, int grid)
{
    const int tid   = threadIdx.x;
    const int lane  = tid & 63;
    const int wv    = tid >> 6;
    const int sub   = lane & 7;
    const int grp   = lane >> 3;
    const int myBin = lane & 15;
    const int e0    = sub * 4;

    const unsigned Noct = N >> 3;                       // octets (8 rows each)
    const unsigned W    = (unsigned)grid * NWAVES;      // total waves = octet stride
    const unsigned gw   = blockIdx.x * NWAVES + wv;     // wave-uniform

    // iterations this wave runs (0 if gw >= Noct)
    const int niter = (gw < Noct) ? (int)((Noct - gw + W - 1) / W) : 0;

    const size_t eStride = (size_t)W << 10;             // floats per octet-stride
    const size_t lStride = (size_t)W << 3;              // labels per octet-stride

    const float* p  = probs  + (((size_t)gw << 3) + grp) * 128 + e0;
    const int*   lp = labels + ((size_t)gw << 3) + grp;

    float cnt = 0.f, cs = 0.f, as_ = 0.f;

    f4 a = {0.f,0.f,0.f,0.f}, b = a, c = a, d = a;
    int lbl = 0;
    if (niter > 0) {
        a = __builtin_nontemporal_load(reinterpret_cast<const f4*>(p));
        b = __builtin_nontemporal_load(reinterpret_cast<const f4*>(p + 32));
        c = __builtin_nontemporal_load(reinterpret_cast<const f4*>(p + 64));
        d = __builtin_nontemporal_load(reinterpret_cast<const f4*>(p + 96));
        lbl = *lp;
    }

    for (int it = 0; it < niter; ++it) {
        const float* pn = p + eStride;

        f4 a2 = {0.f,0.f,0.f,0.f}, b2 = a2, c2 = a2, d2 = a2;
        int lbl2 = 0;
        if (it + 1 < niter) {                            // uniform branch
            a2 = __builtin_nontemporal_load(reinterpret_cast<const f4*>(pn));
            b2 = __builtin_nontemporal_load(reinterpret_cast<const f4*>(pn + 32));
            c2 = __builtin_nontemporal_load(reinterpret_cast<const f4*>(pn + 64));
            d2 = __builtin_nontemporal_load(reinterpret_cast<const f4*>(pn + 96));
            lbl2 = lp[lStride];
        }

        ece_accumulate(a, b, c, d, lbl, sub, myBin, cnt, cs, as_);

        p = pn; lp += lStride;
        a = a2; b = b2; c = c2; d = d2; lbl = lbl2;
    }

    ece_block_reduce_store(cnt, cs, as_, lane, wv, partial, grid);
}

// ---------------------------------------------------------------------------
// GENERIC path (any N): per-row validity masks, identical to R4.
// ---------------------------------------------------------------------------
__global__ __launch_bounds__(BLOCK, 6) void ece_partial_gen(
    const float* __restrict__ probs,
    const int*   __restrict__ labels,
    float*       __restrict__ partial,
    int N, int grid)
{
    const int tid   = threadIdx.x;
    const int lane  = tid & 63;
    const int wv    = tid >> 6;
    const int sub   = lane & 7;
    const int grp   = lane >> 3;
    const int myBin = lane & 15;
    const int e0    = sub * 4;

    const long long gw        = (long long)blockIdx.x * NWAVES + wv;
    const long long rowStride = (long long)grid * NWAVES * 8;

    float cnt = 0.f, cs = 0.f, as_ = 0.f;

    for (long long row0 = gw * 8; row0 < (long long)N; row0 += rowStride) {
        const long long row = row0 + grp;
        const bool rv = row < (long long)N;

        f4 a = {0.f,0.f,0.f,0.f}, b = a, c = a, d = a;
        int lbl = 0;
        if (rv) {
            const float* rp = probs + ((size_t)row << 7) + e0;
            a = __builtin_nontemporal_load(reinterpret_cast<const f4*>(rp));
            b = __builtin_nontemporal_load(reinterpret_cast<const f4*>(rp + 32));
            c = __builtin_nontemporal_load(reinterpret_cast<const f4*>(rp + 64));
            d = __builtin_nontemporal_load(reinterpret_cast<const f4*>(rp + 96));
            lbl = labels[row];
        }
        // invalid rows: all-zero data -> conf=0 -> bin=-1 -> contributes nothing
        ece_accumulate(a, b, c, d, lbl, sub, myBin, cnt, cs, as_);
    }

    ece_block_reduce_store(cnt, cs, as_, lane, wv, partial, grid);
}

// Stage 2: one block, 48x16 threads; coalesced f64 reduction + final ECE.
__global__ __launch_bounds__(S2_THREADS) void ece_final_kernel(
    const float* __restrict__ partial, float* __restrict__ out,
    int grid, int N)
{
    __shared__ double s2[48][16];
    __shared__ double sb[48];
    const int t = threadIdx.x;
    const int comp = t >> 4, sub = t & 15;

    double s = 0.0;
    for (int bk = sub; bk < grid; bk += 16)
        s += (double)partial[(size_t)comp * grid + bk];
    s2[comp][sub] = s;
    __syncthreads();

    if (t < 48) {
        double v = 0.0;
        #pragma unroll
        for (int k = 0; k < 16; ++k) v += s2[t][k];
        sb[t] = v;
    }
    __syncthreads();

    if (t == 0) {
        double ece = 0.0;
        for (int bin = 0; bin < N_BINS; ++bin) {
            const double c0 = sb[bin * 3 + 0];   // count
            const double c1 = sb[bin * 3 + 1];   // conf sum
            const double c2 = sb[bin * 3 + 2];   // acc sum
            if (c0 > 0.0)
                ece += fabs(c1 / c0 - c2 / c0) * (c0 / (double)N);
        }
        out[0] = (float)ece;
    }
}

extern "C" void kernel_launch(void* const* d_in, const int* in_sizes, int n_in,
                              void* d_out, int out_size, void* d_ws, size_t ws_size,
                              hipStream_t stream)
{
    const float* probs  = (const float*)d_in[0];
    const int*   labels = (const int*)d_in[1];
    const int N = in_sizes[1];           // labels count = number of rows
    float* out = (float*)d_out;
    float* partial = (float*)d_ws;

    int grid = GRID_MAX;
    const size_t need_per_block = 48 * sizeof(float);
    if ((size_t)grid * need_per_block > ws_size) {
        grid = (int)(ws_size / need_per_block);
        if (grid < 1) grid = 1;
    }

    if ((N & 7) == 0)
        ece_partial_fast<<<grid, BLOCK, 0, stream>>>(probs, labels, partial,
                                                     (unsigned)N, grid);
    else
        ece_partial_gen<<<grid, BLOCK, 0, stream>>>(probs, labels, partial, N, grid);

    ece_final_kernel<<<1, S2_THREADS, 0, stream>>>(partial, out, grid, N);
}